// Round 3
// baseline (268.905 us; speedup 1.0000x reference)
//
#include <hip/hip_runtime.h>
#include <math.h>

constexpr int T_TOK = 16384;
constexpr int HDIM  = 2048;
constexpr int NEXP  = 64;
constexpr int TPB   = 32;            // tokens per block -> 512 blocks, 2 per CU
constexpr int MT    = TPB / 16;      // 2 m-tiles of 16 tokens
constexpr int NWAVE = 8;
constexpr int KPW   = HDIM / NWAVE;  // 256 k per wave
constexpr int KSTEP = 32;
constexpr int NKS   = KPW / KSTEP;   // 8 k-steps

typedef __attribute__((ext_vector_type(8))) short v8s;   // 8 bf16 (4 VGPRs)
typedef __attribute__((ext_vector_type(4))) float v4f;   // 4 fp32 acc

#define MFMA_BF16 __builtin_amdgcn_mfma_f32_16x16x32_bf16

// Dekker-style truncation split: x = h + m + l exactly to ~24 mantissa bits.
static __device__ __forceinline__ void split3(float x, unsigned short& h,
                                              unsigned short& m, unsigned short& l)
{
    unsigned u0 = __float_as_uint(x);
    h = (unsigned short)(u0 >> 16);
    float r1 = x - __uint_as_float(u0 & 0xFFFF0000u);     // exact
    unsigned u1 = __float_as_uint(r1);
    m = (unsigned short)(u1 >> 16);
    float r2 = r1 - __uint_as_float(u1 & 0xFFFF0000u);    // exact
    l = (unsigned short)(__float_as_uint(r2) >> 16);
}

static __device__ __forceinline__ void frag3(const float4& x0, const float4& x1,
                                             v8s& h, v8s& m, v8s& l)
{
    unsigned short sh, sm, sl;
    split3(x0.x, sh, sm, sl); h[0]=(short)sh; m[0]=(short)sm; l[0]=(short)sl;
    split3(x0.y, sh, sm, sl); h[1]=(short)sh; m[1]=(short)sm; l[1]=(short)sl;
    split3(x0.z, sh, sm, sl); h[2]=(short)sh; m[2]=(short)sm; l[2]=(short)sl;
    split3(x0.w, sh, sm, sl); h[3]=(short)sh; m[3]=(short)sm; l[3]=(short)sl;
    split3(x1.x, sh, sm, sl); h[4]=(short)sh; m[4]=(short)sm; l[4]=(short)sl;
    split3(x1.y, sh, sm, sl); h[5]=(short)sh; m[5]=(short)sm; l[5]=(short)sl;
    split3(x1.z, sh, sm, sl); h[6]=(short)sh; m[6]=(short)sm; l[6]=(short)sl;
    split3(x1.w, sh, sm, sl); h[7]=(short)sh; m[7]=(short)sm; l[7]=(short)sl;
}

// swizzled expert column for the LDS reduction buffer (breaks 4-way write conflicts)
static __device__ __forceinline__ int swz_e(int tok, int e) {
    return e ^ (((tok >> 2) & 1) << 4);
}

// ---------------------------------------------------------------------------
// Prep kernel: split W (64x2048 fp32) into three bf16 planes in workspace.
// Bit-identical to in-loop frag3, so main-kernel numerics are unchanged.
// ---------------------------------------------------------------------------
__global__ __launch_bounds__(256)
void split_w_kernel(const float* __restrict__ W,
                    short* __restrict__ Wh,
                    short* __restrict__ Wm,
                    short* __restrict__ Wl)
{
    const int idx = blockIdx.x * 256 + threadIdx.x;   // 8192 threads x 8 elems
    const float* p = W + (size_t)idx * 8;
    float4 x0 = *(const float4*)p;
    float4 x1 = *(const float4*)(p + 4);
    v8s h, m, l;
    frag3(x0, x1, h, m, l);
    *(v8s*)(Wh + (size_t)idx * 8) = h;
    *(v8s*)(Wm + (size_t)idx * 8) = m;
    *(v8s*)(Wl + (size_t)idx * 8) = l;
}

// ---------------------------------------------------------------------------
// Main kernel: rotating software pipeline.
//  - B pair0 (nt0,1) is loaded ONE ITERATION ahead (full k-step of cover).
//  - B pair1 (nt2,3) is loaded at iteration top, covered by frag3 + pair0 MFMAs.
//  - A(ks+1) issued after frag3(ks), covered by both MFMA blocks + next frag3.
// Live set ~112 unified regs -> fits (512,4)'s 128 budget without spilling.
// ---------------------------------------------------------------------------
__global__ __launch_bounds__(512, 4)
void moe_router_mfma(const float* __restrict__ X,
                     const short* __restrict__ Wh,
                     const short* __restrict__ Wm,
                     const short* __restrict__ Wl,
                     const float* __restrict__ Bg,
                     float* __restrict__ out)
{
    __shared__ float red[4][TPB][NEXP];    // 32 KiB, epilogue only

    const int tid  = threadIdx.x;
    const int lane = tid & 63;
    const int wv   = tid >> 6;             // wave id = k-slice
    const int r16  = lane & 15;
    const int q    = lane >> 4;            // quad id (k-chunk selector)
    const int tok0 = blockIdx.x * TPB;

    // A: lane reads X[tok0 + 16*mt + r16][wv*256 + ks*32 + q*8 .. +7]
    const float* pA = X + (size_t)(tok0 + r16) * HDIM + wv * KPW + q * 8;
    // B: element offset of row r16 within nt-tile 0 at this wave's k-window
    const int ob = r16 * HDIM + wv * KPW + q * 8;   // +32768*nt per n-tile, +32*ks per k-step

    v4f acc[MT][4];
#pragma unroll
    for (int mt = 0; mt < MT; ++mt)
#pragma unroll
        for (int nt = 0; nt < 4; ++nt)
            acc[mt][nt] = (v4f){0.f, 0.f, 0.f, 0.f};

    // ---- prologue: A(0) fp32 and B pair0(0)
    float4 a0[MT], a1[MT];
#pragma unroll
    for (int mt = 0; mt < MT; ++mt) {
        const float* p = pA + (size_t)mt * 16 * HDIM;
        a0[mt] = *(const float4*)p;
        a1[mt] = *(const float4*)(p + 4);
    }
    v8s Bh0 = *(const v8s*)(Wh + ob);
    v8s Bm0 = *(const v8s*)(Wm + ob);
    v8s Bl0 = *(const v8s*)(Wl + ob);
    v8s Bh1 = *(const v8s*)(Wh + 32768 + ob);
    v8s Bm1 = *(const v8s*)(Wm + 32768 + ob);
    v8s Bl1 = *(const v8s*)(Wl + 32768 + ob);

#pragma unroll
    for (int ks = 0; ks < NKS; ++ks) {
        const int ke = ob + ks * KSTEP;

        // ---- 1. issue B pair1(ks): covered by frag3 + pair0 MFMAs
        v8s Bh2 = *(const v8s*)(Wh + 2 * 32768 + ke);
        v8s Bm2 = *(const v8s*)(Wm + 2 * 32768 + ke);
        v8s Bl2 = *(const v8s*)(Wl + 2 * 32768 + ke);
        v8s Bh3 = *(const v8s*)(Wh + 3 * 32768 + ke);
        v8s Bm3 = *(const v8s*)(Wm + 3 * 32768 + ke);
        v8s Bl3 = *(const v8s*)(Wl + 3 * 32768 + ke);

        // ---- 2. split A(ks) fp32 -> bf16 triples (a0/a1 die here)
        v8s Ah[MT], Am[MT], Al[MT];
#pragma unroll
        for (int mt = 0; mt < MT; ++mt) frag3(a0[mt], a1[mt], Ah[mt], Am[mt], Al[mt]);

        // ---- 3. prefetch A(ks+1): covered by both MFMA blocks + next frag3
        if (ks < NKS - 1) {
            const int off = (ks + 1) * KSTEP;
#pragma unroll
            for (int mt = 0; mt < MT; ++mt) {
                const float* p = pA + (size_t)mt * 16 * HDIM + off;
                a0[mt] = *(const float4*)p;
                a1[mt] = *(const float4*)(p + 4);
            }
        }

        // ---- 4. MFMA pair0(ks): B regs loaded one iteration ago (full cover)
#pragma unroll
        for (int mt = 0; mt < MT; ++mt) {
            v4f a = acc[mt][0];
            a = MFMA_BF16(Ah[mt], Bh0, a, 0, 0, 0);
            a = MFMA_BF16(Ah[mt], Bm0, a, 0, 0, 0);
            a = MFMA_BF16(Am[mt], Bh0, a, 0, 0, 0);
            a = MFMA_BF16(Ah[mt], Bl0, a, 0, 0, 0);
            a = MFMA_BF16(Al[mt], Bh0, a, 0, 0, 0);
            a = MFMA_BF16(Am[mt], Bm0, a, 0, 0, 0);
            acc[mt][0] = a;
            v4f b = acc[mt][1];
            b = MFMA_BF16(Ah[mt], Bh1, b, 0, 0, 0);
            b = MFMA_BF16(Ah[mt], Bm1, b, 0, 0, 0);
            b = MFMA_BF16(Am[mt], Bh1, b, 0, 0, 0);
            b = MFMA_BF16(Ah[mt], Bl1, b, 0, 0, 0);
            b = MFMA_BF16(Al[mt], Bh1, b, 0, 0, 0);
            b = MFMA_BF16(Am[mt], Bm1, b, 0, 0, 0);
            acc[mt][1] = b;
        }

        // ---- 5. issue B pair0(ks+1) into the now-dead pair0 registers
        if (ks < NKS - 1) {
            const int kn = ke + KSTEP;
            Bh0 = *(const v8s*)(Wh + kn);
            Bm0 = *(const v8s*)(Wm + kn);
            Bl0 = *(const v8s*)(Wl + kn);
            Bh1 = *(const v8s*)(Wh + 32768 + kn);
            Bm1 = *(const v8s*)(Wm + 32768 + kn);
            Bl1 = *(const v8s*)(Wl + 32768 + kn);
        }

        // ---- 6. MFMA pair1(ks)
#pragma unroll
        for (int mt = 0; mt < MT; ++mt) {
            v4f a = acc[mt][2];
            a = MFMA_BF16(Ah[mt], Bh2, a, 0, 0, 0);
            a = MFMA_BF16(Ah[mt], Bm2, a, 0, 0, 0);
            a = MFMA_BF16(Am[mt], Bh2, a, 0, 0, 0);
            a = MFMA_BF16(Ah[mt], Bl2, a, 0, 0, 0);
            a = MFMA_BF16(Al[mt], Bh2, a, 0, 0, 0);
            a = MFMA_BF16(Am[mt], Bm2, a, 0, 0, 0);
            acc[mt][2] = a;
            v4f b = acc[mt][3];
            b = MFMA_BF16(Ah[mt], Bh3, b, 0, 0, 0);
            b = MFMA_BF16(Ah[mt], Bm3, b, 0, 0, 0);
            b = MFMA_BF16(Am[mt], Bh3, b, 0, 0, 0);
            b = MFMA_BF16(Ah[mt], Bl3, b, 0, 0, 0);
            b = MFMA_BF16(Al[mt], Bh3, b, 0, 0, 0);
            b = MFMA_BF16(Am[mt], Bm3, b, 0, 0, 0);
            acc[mt][3] = b;
        }
    }

    // ---- cross-wave K reduction: 4 slots, two phases
    // C/D layout: col(expert-local) = lane&15, row(token-local) = q*4 + r
    if (wv < 4) {
#pragma unroll
        for (int mt = 0; mt < MT; ++mt)
#pragma unroll
            for (int nt = 0; nt < 4; ++nt)
#pragma unroll
                for (int r = 0; r < 4; ++r) {
                    int tok = 16 * mt + q * 4 + r;
                    int e   = 16 * nt + r16;
                    red[wv][tok][swz_e(tok, e)] = acc[mt][nt][r];
                }
    }
    __syncthreads();
    if (wv >= 4) {
#pragma unroll
        for (int mt = 0; mt < MT; ++mt)
#pragma unroll
            for (int nt = 0; nt < 4; ++nt)
#pragma unroll
                for (int r = 0; r < 4; ++r) {
                    int tok = 16 * mt + q * 4 + r;
                    int e   = 16 * nt + r16;
                    red[wv - 4][tok][swz_e(tok, e)] += acc[mt][nt][r];
                }
    }
    __syncthreads();

    // ---- epilogue: 4 tokens/wave on lanes 0..3
    // lg[] indexed by eo (STATIC -> registers); e = (eo + 16*lane) & 63
    // rotation staggers LDS banks (tk stride 64 floats -> same bank otherwise)
    if (lane < 4) {
        const int tk = wv * 4 + lane;
        const int t  = tok0 + tk;
        const int sh = lane << 4;            // 0,16,32,48
        float lg[NEXP];
#pragma unroll
        for (int eo = 0; eo < NEXP; ++eo) {
            int e  = (eo + sh) & (NEXP - 1);
            int es = swz_e(tk, e);
            lg[eo] = ((red[0][tk][es] + red[1][tk][es]) +
                      (red[2][tk][es] + red[3][tk][es])) + Bg[e];
        }
        float* outL = out + (size_t)t * NEXP;
#pragma unroll
        for (int eo = 0; eo < NEXP; eo += 4) {
            int e = (eo + sh) & (NEXP - 1);  // sh multiple of 16 -> blocks stay contiguous
            float4 v = make_float4(lg[eo], lg[eo+1], lg[eo+2], lg[eo+3]);
            *(float4*)(outL + e) = v;
        }
        // softmax + top-2 are permutation-invariant over eo; map indices at end
        float mx = lg[0];
#pragma unroll
        for (int eo = 1; eo < NEXP; ++eo) mx = fmaxf(mx, lg[eo]);
        float S = 0.f;
#pragma unroll
        for (int eo = 0; eo < NEXP; ++eo) { lg[eo] = expf(lg[eo] - mx); S += lg[eo]; }
#pragma unroll
        for (int eo = 0; eo < NEXP; ++eo) lg[eo] = lg[eo] / S;

        float v1 = lg[0]; int i1o = 0;
        float v2 = -1.0f; int i2o = 0;
#pragma unroll
        for (int eo = 1; eo < NEXP; ++eo) {
            float rv = lg[eo];
            bool g1 = rv > v1;
            bool g2 = rv > v2;
            float nv2 = g1 ? v1 : (g2 ? rv : v2);
            int   ni2 = g1 ? i1o : (g2 ? eo : i2o);
            v2 = nv2; i2o = ni2;
            v1 = g1 ? rv : v1;
            i1o = g1 ? eo : i1o;
        }
        const int i1 = (i1o + sh) & (NEXP - 1);
        const int i2 = (i2o + sh) & (NEXP - 1);
        float den = v1 + v2;
        float w1 = v1 / den, w2 = v2 / den;

        float* outW = out + (size_t)T_TOK * NEXP;
        float* outS = outW + (size_t)T_TOK * 2;
        float* outM = outS + (size_t)T_TOK * 2;
        outW[2*t+0] = w1;        outW[2*t+1] = w2;
        outS[2*t+0] = (float)i1; outS[2*t+1] = (float)i2;

        float* mrow = outM + (size_t)t * 2 * NEXP;
#pragma unroll
        for (int e = 0; e < NEXP; e += 4) {
            float4 a = make_float4(e+0==i1?1.f:0.f, e+1==i1?1.f:0.f,
                                   e+2==i1?1.f:0.f, e+3==i1?1.f:0.f);
            *(float4*)(mrow + e) = a;
            float4 b = make_float4(e+0==i2?1.f:0.f, e+1==i2?1.f:0.f,
                                   e+2==i2?1.f:0.f, e+3==i2?1.f:0.f);
            *(float4*)(mrow + NEXP + e) = b;
        }
    }
}

extern "C" void kernel_launch(void* const* d_in, const int* in_sizes, int n_in,
                              void* d_out, int out_size, void* d_ws, size_t ws_size,
                              hipStream_t stream)
{
    const float* X = (const float*)d_in[0];
    const float* W = (const float*)d_in[1];
    const float* B = (const float*)d_in[2];
    float* out     = (float*)d_out;

    // workspace: three bf16 planes of W, 64*2048*2 B each = 768 KiB total
    short* Wh = (short*)d_ws;
    short* Wm = Wh + NEXP * HDIM;
    short* Wl = Wm + NEXP * HDIM;

    hipLaunchKernelGGL(split_w_kernel, dim3(NEXP * HDIM / 8 / 256), dim3(256),
                       0, stream, W, Wh, Wm, Wl);
    hipLaunchKernelGGL(moe_router_mfma, dim3(T_TOK / TPB), dim3(512),
                       0, stream, X, Wh, Wm, Wl, B, out);
}

// Round 4
// 246.360 us; speedup vs baseline: 1.0915x; 1.0915x over previous
//
#include <hip/hip_runtime.h>
#include <math.h>

constexpr int T_TOK = 16384;
constexpr int HDIM  = 2048;
constexpr int NEXP  = 64;
constexpr int TPB   = 32;            // tokens per block -> 512 blocks, 2 per CU
constexpr int MT    = TPB / 16;      // 2 m-tiles of 16 tokens
constexpr int NWAVE = 8;
constexpr int KPW   = HDIM / NWAVE;  // 256 k per wave
constexpr int KSTEP = 32;
constexpr int NKS   = KPW / KSTEP;   // 8 k-steps

typedef __attribute__((ext_vector_type(8))) short v8s;   // 8 bf16 (4 VGPRs)
typedef __attribute__((ext_vector_type(4))) float v4f;   // 4 fp32 acc

#define MFMA_BF16 __builtin_amdgcn_mfma_f32_16x16x32_bf16

// Dekker-style truncation split: x = h + m + l exactly to ~24 mantissa bits.
static __device__ __forceinline__ void split3(float x, unsigned short& h,
                                              unsigned short& m, unsigned short& l)
{
    unsigned u0 = __float_as_uint(x);
    h = (unsigned short)(u0 >> 16);
    float r1 = x - __uint_as_float(u0 & 0xFFFF0000u);     // exact
    unsigned u1 = __float_as_uint(r1);
    m = (unsigned short)(u1 >> 16);
    float r2 = r1 - __uint_as_float(u1 & 0xFFFF0000u);    // exact
    l = (unsigned short)(__float_as_uint(r2) >> 16);
}

static __device__ __forceinline__ void frag3(const float4& x0, const float4& x1,
                                             v8s& h, v8s& m, v8s& l)
{
    unsigned short sh, sm, sl;
    split3(x0.x, sh, sm, sl); h[0]=(short)sh; m[0]=(short)sm; l[0]=(short)sl;
    split3(x0.y, sh, sm, sl); h[1]=(short)sh; m[1]=(short)sm; l[1]=(short)sl;
    split3(x0.z, sh, sm, sl); h[2]=(short)sh; m[2]=(short)sm; l[2]=(short)sl;
    split3(x0.w, sh, sm, sl); h[3]=(short)sh; m[3]=(short)sm; l[3]=(short)sl;
    split3(x1.x, sh, sm, sl); h[4]=(short)sh; m[4]=(short)sm; l[4]=(short)sl;
    split3(x1.y, sh, sm, sl); h[5]=(short)sh; m[5]=(short)sm; l[5]=(short)sl;
    split3(x1.z, sh, sm, sl); h[6]=(short)sh; m[6]=(short)sm; l[6]=(short)sl;
    split3(x1.w, sh, sm, sl); h[7]=(short)sh; m[7]=(short)sm; l[7]=(short)sl;
}

// swizzled expert column for the LDS reduction buffer (breaks 4-way write conflicts)
static __device__ __forceinline__ int swz_e(int tok, int e) {
    return e ^ (((tok >> 2) & 1) << 4);
}

// ---------------------------------------------------------------------------
// Prep kernel: split W AND pack it in MFMA-fragment order.
// Output chunk index (16 B, one lane's v8s fragment):
//   chunk = ((wv*8 + ks)*12 + nt*3 + plane)*64 + lane
// so the main kernel's B load is base + lane*16: perfectly coalesced.
// Split values are bit-identical to in-loop frag3 -> numerics unchanged.
// 49152 chunks = 768 KiB.
// ---------------------------------------------------------------------------
__global__ __launch_bounds__(256)
void pack_w_kernel(const float* __restrict__ W, short* __restrict__ P)
{
    const int tid = blockIdx.x * 256 + threadIdx.x;   // 0..49151
    const int l   = tid & 63;
    int g = tid >> 6;
    const int p  = g % 3;  g /= 3;
    const int nt = g % 4;  g /= 4;
    const int ks = g % 8;
    const int wv = g / 8;
    const int r16 = l & 15, q = l >> 4;
    const float* src = W + (size_t)(nt * 16 + r16) * HDIM + wv * KPW + ks * KSTEP + q * 8;
    float4 x0 = *(const float4*)src;
    float4 x1 = *(const float4*)(src + 4);
    v8s h, m, lo;
    frag3(x0, x1, h, m, lo);
    v8s outv = (p == 0) ? h : (p == 1) ? m : lo;
    *(v8s*)(P + (size_t)tid * 8) = outv;
}

// ---------------------------------------------------------------------------
// Main kernel.
//  A path: wave reg-stages its PRIVATE 4 KB X window (coalesced lane*16 global
//  reads) into an XOR-swizzled LDS slice, then ds_read_b128 the MFMA fragments
//  (conflict-free). No cross-wave sharing -> ZERO barriers in the K-loop.
//  B path: packed-fragment global loads, base + lane*16, contiguous.
//  This removes the 16-segment address divergence that made rounds 0-3
//  L1-transaction-bound.
// ---------------------------------------------------------------------------
__global__ __launch_bounds__(512, 4)
void moe_router_mfma(const float* __restrict__ X,
                     const short* __restrict__ Pw,
                     const float* __restrict__ Bg,
                     float* __restrict__ out)
{
    // 64 KiB: K-loop = per-wave xbuf[8][2 buf][32 tok][32 k] fp32;
    // epilogue (after barrier) = red[4][32][64] fp32 (32 KiB, aliased).
    __shared__ float smem[16384];

    const int tid  = threadIdx.x;
    const int lane = tid & 63;
    const int wv   = tid >> 6;             // wave id = k-slice
    const int r16  = lane & 15;
    const int q    = lane >> 4;            // quad id (k-chunk selector)
    const int tok0 = blockIdx.x * TPB;

    // ---- staging constants (writer): lane covers (tok = j*8 + (lane>>3), chunk c = lane&7)
    const int wrow = (lane >> 3);                        // tok&7 for this lane's rows
    const int sc   = ((lane & 7) ^ wrow) * 4;            // swizzled chunk, float offset
    const int srow = wrow * 32;                          // row float offset (+ j*256)
    const float* pS = X + (size_t)(tok0 + wrow) * HDIM + wv * KPW + (lane & 7) * 4;

    // ---- reader constants: logical chunks 2q, 2q+1 -> phys = chunk ^ (r16&7)
    const int xslice  = wv * 2048;                       // float offset of wave slice (2 bufs)
    const int rchunk0 = ((2 * q)     ^ (r16 & 7)) * 4;
    const int rchunk1 = ((2 * q + 1) ^ (r16 & 7)) * 4;

    // ---- B: packed fragment pointer (chunk = ((wv*8+ks)*12 + nt*3 + p)*64 + lane)
    const short* pBw = Pw + (size_t)(wv * 8) * 12 * 512 + lane * 8;

    v4f acc[MT][4];
#pragma unroll
    for (int mt = 0; mt < MT; ++mt)
#pragma unroll
        for (int nt = 0; nt < 4; ++nt)
            acc[mt][nt] = (v4f){0.f, 0.f, 0.f, 0.f};

    // ---- prologue: stage window ks=0 into buf 0
    {
        float4 g0 = *(const float4*)(pS + 0 * 8 * HDIM);
        float4 g1 = *(const float4*)(pS + 1 * 8 * HDIM);
        float4 g2 = *(const float4*)(pS + 2 * 8 * HDIM);
        float4 g3 = *(const float4*)(pS + 3 * 8 * HDIM);
        *(float4*)&smem[xslice + 0 * 256 + srow + sc] = g0;
        *(float4*)&smem[xslice + 1 * 256 + srow + sc] = g1;
        *(float4*)&smem[xslice + 2 * 256 + srow + sc] = g2;
        *(float4*)&smem[xslice + 3 * 256 + srow + sc] = g3;
    }

    for (int ks = 0; ks < NKS; ++ks) {
        const int cur = (ks & 1) * 1024;
        const int nxt = ((ks + 1) & 1) * 1024;
        const short* pBk = pBw + ks * 6144;   // 12 chunks * 512 shorts

        // ---- issue A-stage global loads for window ks+1 (coalesced, 8 lines each)
        float4 g0, g1, g2, g3;
        if (ks < NKS - 1) {
            const float* pSn = pS + (ks + 1) * KSTEP;
            g0 = *(const float4*)(pSn + 0 * 8 * HDIM);
            g1 = *(const float4*)(pSn + 1 * 8 * HDIM);
            g2 = *(const float4*)(pSn + 2 * 8 * HDIM);
            g3 = *(const float4*)(pSn + 3 * 8 * HDIM);
        }

        // ---- read A fragments (fp32) from own LDS slice, split to bf16 triples
        v8s Ah[MT], Am[MT], Al[MT];
#pragma unroll
        for (int mt = 0; mt < MT; ++mt) {
            const int rowb = xslice + cur + (16 * mt + r16) * 32;
            float4 a0 = *(const float4*)&smem[rowb + rchunk0];
            float4 a1 = *(const float4*)&smem[rowb + rchunk1];
            frag3(a0, a1, Ah[mt], Am[mt], Al[mt]);
        }

        // ---- B pair0 (nt=0,1): contiguous packed loads
        v8s Bh0 = *(const v8s*)(pBk + 0 * 512);
        v8s Bm0 = *(const v8s*)(pBk + 1 * 512);
        v8s Bl0 = *(const v8s*)(pBk + 2 * 512);
        v8s Bh1 = *(const v8s*)(pBk + 3 * 512);
        v8s Bm1 = *(const v8s*)(pBk + 4 * 512);
        v8s Bl1 = *(const v8s*)(pBk + 5 * 512);

        // ---- MFMA pair0
#pragma unroll
        for (int mt = 0; mt < MT; ++mt) {
            v4f a = acc[mt][0];
            a = MFMA_BF16(Ah[mt], Bh0, a, 0, 0, 0);
            a = MFMA_BF16(Ah[mt], Bm0, a, 0, 0, 0);
            a = MFMA_BF16(Am[mt], Bh0, a, 0, 0, 0);
            a = MFMA_BF16(Ah[mt], Bl0, a, 0, 0, 0);
            a = MFMA_BF16(Al[mt], Bh0, a, 0, 0, 0);
            a = MFMA_BF16(Am[mt], Bm0, a, 0, 0, 0);
            acc[mt][0] = a;
            v4f b = acc[mt][1];
            b = MFMA_BF16(Ah[mt], Bh1, b, 0, 0, 0);
            b = MFMA_BF16(Ah[mt], Bm1, b, 0, 0, 0);
            b = MFMA_BF16(Am[mt], Bh1, b, 0, 0, 0);
            b = MFMA_BF16(Ah[mt], Bl1, b, 0, 0, 0);
            b = MFMA_BF16(Al[mt], Bh1, b, 0, 0, 0);
            b = MFMA_BF16(Am[mt], Bm1, b, 0, 0, 0);
            acc[mt][1] = b;
        }

        // ---- write staged window ks+1 into the other buffer (private slice)
        if (ks < NKS - 1) {
            *(float4*)&smem[xslice + nxt + 0 * 256 + srow + sc] = g0;
            *(float4*)&smem[xslice + nxt + 1 * 256 + srow + sc] = g1;
            *(float4*)&smem[xslice + nxt + 2 * 256 + srow + sc] = g2;
            *(float4*)&smem[xslice + nxt + 3 * 256 + srow + sc] = g3;
        }

        // ---- B pair1 (nt=2,3)
        v8s Bh2 = *(const v8s*)(pBk + 6 * 512);
        v8s Bm2 = *(const v8s*)(pBk + 7 * 512);
        v8s Bl2 = *(const v8s*)(pBk + 8 * 512);
        v8s Bh3 = *(const v8s*)(pBk + 9 * 512);
        v8s Bm3 = *(const v8s*)(pBk + 10 * 512);
        v8s Bl3 = *(const v8s*)(pBk + 11 * 512);

        // ---- MFMA pair1
#pragma unroll
        for (int mt = 0; mt < MT; ++mt) {
            v4f a = acc[mt][2];
            a = MFMA_BF16(Ah[mt], Bh2, a, 0, 0, 0);
            a = MFMA_BF16(Ah[mt], Bm2, a, 0, 0, 0);
            a = MFMA_BF16(Am[mt], Bh2, a, 0, 0, 0);
            a = MFMA_BF16(Ah[mt], Bl2, a, 0, 0, 0);
            a = MFMA_BF16(Al[mt], Bh2, a, 0, 0, 0);
            a = MFMA_BF16(Am[mt], Bm2, a, 0, 0, 0);
            acc[mt][2] = a;
            v4f b = acc[mt][3];
            b = MFMA_BF16(Ah[mt], Bh3, b, 0, 0, 0);
            b = MFMA_BF16(Ah[mt], Bm3, b, 0, 0, 0);
            b = MFMA_BF16(Am[mt], Bh3, b, 0, 0, 0);
            b = MFMA_BF16(Ah[mt], Bl3, b, 0, 0, 0);
            b = MFMA_BF16(Al[mt], Bh3, b, 0, 0, 0);
            b = MFMA_BF16(Am[mt], Bm3, b, 0, 0, 0);
            acc[mt][3] = b;
        }
    }

    // ---- reuse smem as red[4][32][64] (all waves done with xbuf after this barrier)
    __syncthreads();
    float (*red)[TPB][NEXP] = (float (*)[TPB][NEXP])smem;

    if (wv < 4) {
#pragma unroll
        for (int mt = 0; mt < MT; ++mt)
#pragma unroll
            for (int nt = 0; nt < 4; ++nt)
#pragma unroll
                for (int r = 0; r < 4; ++r) {
                    int tok = 16 * mt + q * 4 + r;
                    int e   = 16 * nt + r16;
                    red[wv][tok][swz_e(tok, e)] = acc[mt][nt][r];
                }
    }
    __syncthreads();
    if (wv >= 4) {
#pragma unroll
        for (int mt = 0; mt < MT; ++mt)
#pragma unroll
            for (int nt = 0; nt < 4; ++nt)
#pragma unroll
                for (int r = 0; r < 4; ++r) {
                    int tok = 16 * mt + q * 4 + r;
                    int e   = 16 * nt + r16;
                    red[wv - 4][tok][swz_e(tok, e)] += acc[mt][nt][r];
                }
    }
    __syncthreads();

    // ---- epilogue: 4 tokens/wave on lanes 0..3
    // lg[] indexed by eo (STATIC -> registers); e = (eo + 16*lane) & 63
    // rotation staggers LDS banks (tk stride 64 floats -> same bank otherwise)
    if (lane < 4) {
        const int tk = wv * 4 + lane;
        const int t  = tok0 + tk;
        const int sh = lane << 4;            // 0,16,32,48
        float lg[NEXP];
#pragma unroll
        for (int eo = 0; eo < NEXP; ++eo) {
            int e  = (eo + sh) & (NEXP - 1);
            int es = swz_e(tk, e);
            lg[eo] = ((red[0][tk][es] + red[1][tk][es]) +
                      (red[2][tk][es] + red[3][tk][es])) + Bg[e];
        }
        float* outL = out + (size_t)t * NEXP;
#pragma unroll
        for (int eo = 0; eo < NEXP; eo += 4) {
            int e = (eo + sh) & (NEXP - 1);  // sh multiple of 16 -> blocks stay contiguous
            float4 v = make_float4(lg[eo], lg[eo+1], lg[eo+2], lg[eo+3]);
            *(float4*)(outL + e) = v;
        }
        float mx = lg[0];
#pragma unroll
        for (int eo = 1; eo < NEXP; ++eo) mx = fmaxf(mx, lg[eo]);
        float S = 0.f;
#pragma unroll
        for (int eo = 0; eo < NEXP; ++eo) { lg[eo] = expf(lg[eo] - mx); S += lg[eo]; }
#pragma unroll
        for (int eo = 0; eo < NEXP; ++eo) lg[eo] = lg[eo] / S;

        float v1 = lg[0]; int i1o = 0;
        float v2 = -1.0f; int i2o = 0;
#pragma unroll
        for (int eo = 1; eo < NEXP; ++eo) {
            float rv = lg[eo];
            bool g1 = rv > v1;
            bool g2 = rv > v2;
            float nv2 = g1 ? v1 : (g2 ? rv : v2);
            int   ni2 = g1 ? i1o : (g2 ? eo : i2o);
            v2 = nv2; i2o = ni2;
            v1 = g1 ? rv : v1;
            i1o = g1 ? eo : i1o;
        }
        const int i1 = (i1o + sh) & (NEXP - 1);
        const int i2 = (i2o + sh) & (NEXP - 1);
        float den = v1 + v2;
        float w1 = v1 / den, w2 = v2 / den;

        float* outW = out + (size_t)T_TOK * NEXP;
        float* outS = outW + (size_t)T_TOK * 2;
        float* outM = outS + (size_t)T_TOK * 2;
        outW[2*t+0] = w1;        outW[2*t+1] = w2;
        outS[2*t+0] = (float)i1; outS[2*t+1] = (float)i2;

        float* mrow = outM + (size_t)t * 2 * NEXP;
#pragma unroll
        for (int e = 0; e < NEXP; e += 4) {
            float4 a = make_float4(e+0==i1?1.f:0.f, e+1==i1?1.f:0.f,
                                   e+2==i1?1.f:0.f, e+3==i1?1.f:0.f);
            *(float4*)(mrow + e) = a;
            float4 b = make_float4(e+0==i2?1.f:0.f, e+1==i2?1.f:0.f,
                                   e+2==i2?1.f:0.f, e+3==i2?1.f:0.f);
            *(float4*)(mrow + NEXP + e) = b;
        }
    }
}

extern "C" void kernel_launch(void* const* d_in, const int* in_sizes, int n_in,
                              void* d_out, int out_size, void* d_ws, size_t ws_size,
                              hipStream_t stream)
{
    const float* X = (const float*)d_in[0];
    const float* W = (const float*)d_in[1];
    const float* B = (const float*)d_in[2];
    float* out     = (float*)d_out;

    // workspace: packed W fragments, 49152 chunks * 16 B = 768 KiB
    short* Pw = (short*)d_ws;

    hipLaunchKernelGGL(pack_w_kernel, dim3(49152 / 256), dim3(256),
                       0, stream, W, Pw);
    hipLaunchKernelGGL(moe_router_mfma, dim3(T_TOK / TPB), dim3(512),
                       0, stream, X, Pw, B, out);
}

// Round 5
// 228.748 us; speedup vs baseline: 1.1756x; 1.0770x over previous
//
#include <hip/hip_runtime.h>
#include <math.h>

constexpr int T_TOK = 16384;
constexpr int HDIM  = 2048;
constexpr int NEXP  = 64;
constexpr int TPB   = 64;            // tokens per block -> 256 blocks (halves B re-read traffic)
constexpr int MT    = TPB / 16;      // 4 m-tiles of 16 tokens
constexpr int NWAVE = 8;
constexpr int KPW   = HDIM / NWAVE;  // 256 k per wave
constexpr int KSTEP = 32;
constexpr int NKS   = KPW / KSTEP;   // 8 k-steps

typedef __attribute__((ext_vector_type(8))) short v8s;   // 8 bf16 (4 VGPRs)
typedef __attribute__((ext_vector_type(4))) float v4f;   // 4 fp32 acc

#define MFMA_BF16 __builtin_amdgcn_mfma_f32_16x16x32_bf16

// Dekker-style truncation split: x = h + m + l exactly to ~24 mantissa bits.
static __device__ __forceinline__ void split3(float x, unsigned short& h,
                                              unsigned short& m, unsigned short& l)
{
    unsigned u0 = __float_as_uint(x);
    h = (unsigned short)(u0 >> 16);
    float r1 = x - __uint_as_float(u0 & 0xFFFF0000u);     // exact
    unsigned u1 = __float_as_uint(r1);
    m = (unsigned short)(u1 >> 16);
    float r2 = r1 - __uint_as_float(u1 & 0xFFFF0000u);    // exact
    l = (unsigned short)(__float_as_uint(r2) >> 16);
}

static __device__ __forceinline__ void frag3(const float4& x0, const float4& x1,
                                             v8s& h, v8s& m, v8s& l)
{
    unsigned short sh, sm, sl;
    split3(x0.x, sh, sm, sl); h[0]=(short)sh; m[0]=(short)sm; l[0]=(short)sl;
    split3(x0.y, sh, sm, sl); h[1]=(short)sh; m[1]=(short)sm; l[1]=(short)sl;
    split3(x0.z, sh, sm, sl); h[2]=(short)sh; m[2]=(short)sm; l[2]=(short)sl;
    split3(x0.w, sh, sm, sl); h[3]=(short)sh; m[3]=(short)sm; l[3]=(short)sl;
    split3(x1.x, sh, sm, sl); h[4]=(short)sh; m[4]=(short)sm; l[4]=(short)sl;
    split3(x1.y, sh, sm, sl); h[5]=(short)sh; m[5]=(short)sm; l[5]=(short)sl;
    split3(x1.z, sh, sm, sl); h[6]=(short)sh; m[6]=(short)sm; l[6]=(short)sl;
    split3(x1.w, sh, sm, sl); h[7]=(short)sh; m[7]=(short)sm; l[7]=(short)sl;
}

// swizzled expert column for the LDS reduction buffer (breaks 4-way write conflicts)
static __device__ __forceinline__ int swz_e(int tok, int e) {
    return e ^ (((tok >> 2) & 1) << 4);
}

// ---------------------------------------------------------------------------
// Prep kernel: split W AND pack it in MFMA-fragment order (round-4 proven).
//   chunk = ((wv*8 + ks)*12 + nt*3 + plane)*64 + lane   (16 B per chunk-lane)
// Main-kernel B loads become base + lane*16: perfectly coalesced.
// Bit-identical to in-loop frag3 -> numerics unchanged. 768 KiB.
// ---------------------------------------------------------------------------
__global__ __launch_bounds__(256)
void pack_w_kernel(const float* __restrict__ W, short* __restrict__ P)
{
    const int tid = blockIdx.x * 256 + threadIdx.x;   // 0..49151
    const int l   = tid & 63;
    int g = tid >> 6;
    const int p  = g % 3;  g /= 3;
    const int nt = g % 4;  g /= 4;
    const int ks = g % 8;
    const int wv = g / 8;
    const int r16 = l & 15, q = l >> 4;
    const float* src = W + (size_t)(nt * 16 + r16) * HDIM + wv * KPW + ks * KSTEP + q * 8;
    float4 x0 = *(const float4*)src;
    float4 x1 = *(const float4*)(src + 4);
    v8s h, m, lo;
    frag3(x0, x1, h, m, lo);
    v8s outv = (p == 0) ? h : (p == 1) ? m : lo;
    *(v8s*)(P + (size_t)tid * 8) = outv;
}

// ---------------------------------------------------------------------------
// Main kernel (TPB=64, 8 waves, K-split 8).
//  - A: wave-private 8 KiB LDS window, double-buffered (no barriers in K-loop).
//    Coalesced reg-staging writes, XOR-swizzled chunks, conflict-minimal reads.
//  - B: packed-fragment coalesced loads, prefetched ONE FULL k-step ahead.
//  - (512,2): 256 unified regs -> live set (~200) fits without spilling.
// ---------------------------------------------------------------------------
__global__ __launch_bounds__(512, 2)
void moe_router_mfma(const float* __restrict__ X,
                     const short* __restrict__ Pw,
                     const float* __restrict__ Bg,
                     float* __restrict__ out)
{
    // 128 KiB: K-loop = per-wave xbuf[8 waves][2 buf][64 tok][32 k] fp32.
    // Epilogue red[4][64][64] (64 KiB) aliases waves 0-3's slices exactly.
    __shared__ float smem[32768];

    const int tid  = threadIdx.x;
    const int lane = tid & 63;
    const int wv   = tid >> 6;             // wave id = k-slice
    const int r16  = lane & 15;
    const int q    = lane >> 4;            // quad id (k-chunk selector)
    const int tok0 = blockIdx.x * TPB;

    // ---- staging (writer): lane covers rows {j*8 + (lane>>3)}, logical chunk lane&7
    const int wrow = lane >> 3;
    const int lc   = lane & 7;
    const int sc   = (lc ^ wrow) * 4;                    // swizzled chunk, float offset
    const float* pS = X + (size_t)(tok0 + wrow) * HDIM + wv * KPW + lc * 4;

    // ---- reader: logical chunks 2q, 2q+1 -> phys = chunk ^ (r16&7)
    const int xsl = wv * 4096;                           // float offset of wave slice (2 bufs)
    const int rc0 = ((2 * q)     ^ (r16 & 7)) * 4;
    const int rc1 = ((2 * q + 1) ^ (r16 & 7)) * 4;

    // ---- B: packed fragment pointer
    const short* pBw = Pw + (size_t)(wv * 8) * 12 * 512 + lane * 8;

    v4f acc[MT][4];
#pragma unroll
    for (int mt = 0; mt < MT; ++mt)
#pragma unroll
        for (int nt = 0; nt < 4; ++nt)
            acc[mt][nt] = (v4f){0.f, 0.f, 0.f, 0.f};

    // ---- prologue: stage window ks=0 into buf 0; load B(0)
#pragma unroll
    for (int j = 0; j < 8; ++j) {
        float4 gv = *(const float4*)(pS + (size_t)j * 8 * HDIM);
        *(float4*)&smem[xsl + (j * 8 + wrow) * 32 + sc] = gv;
    }
    v8s Bc[12];
#pragma unroll
    for (int c = 0; c < 12; ++c) Bc[c] = *(const v8s*)(pBw + c * 512);

#pragma unroll
    for (int ks = 0; ks < NKS; ++ks) {
        const int cur = xsl + (ks & 1) * 2048;
        const int nxt = xsl + ((ks + 1) & 1) * 2048;

        // ---- issue A-global loads for window ks+1 (coalesced; longest latency first)
        float4 g[8];
        if (ks < NKS - 1) {
#pragma unroll
            for (int j = 0; j < 8; ++j)
                g[j] = *(const float4*)(pS + (size_t)j * 8 * HDIM + (ks + 1) * KSTEP);
        }

        // ---- issue B loads for ks+1 (consumed NEXT iteration: full k-step of cover)
        v8s Bn[12];
        if (ks < NKS - 1) {
            const short* pBk = pBw + (ks + 1) * 6144;   // 12 chunks * 512 shorts
#pragma unroll
            for (int c = 0; c < 12; ++c) Bn[c] = *(const v8s*)(pBk + c * 512);
        }

        // ---- read all A fragments (fp32) from own LDS slice
        float4 a0[MT], a1[MT];
#pragma unroll
        for (int mt = 0; mt < MT; ++mt) {
            const int rowb = cur + (16 * mt + r16) * 32;
            a0[mt] = *(const float4*)&smem[rowb + rc0];
            a1[mt] = *(const float4*)&smem[rowb + rc1];
        }

        // ---- per m-tile: split + 24 MFMAs (frag3 of mt co-issues with MFMAs of mt-1)
#pragma unroll
        for (int mt = 0; mt < MT; ++mt) {
            v8s Ah, Am, Al;
            frag3(a0[mt], a1[mt], Ah, Am, Al);
#pragma unroll
            for (int nt = 0; nt < 4; ++nt) {
                v4f a = acc[mt][nt];
                a = MFMA_BF16(Ah, Bc[nt * 3 + 0], a, 0, 0, 0);
                a = MFMA_BF16(Ah, Bc[nt * 3 + 1], a, 0, 0, 0);
                a = MFMA_BF16(Am, Bc[nt * 3 + 0], a, 0, 0, 0);
                a = MFMA_BF16(Ah, Bc[nt * 3 + 2], a, 0, 0, 0);
                a = MFMA_BF16(Al, Bc[nt * 3 + 0], a, 0, 0, 0);
                a = MFMA_BF16(Am, Bc[nt * 3 + 1], a, 0, 0, 0);
                acc[mt][nt] = a;
            }
        }

        // ---- write staged window ks+1 (private slice, other buffer) + rotate B
        if (ks < NKS - 1) {
#pragma unroll
            for (int j = 0; j < 8; ++j)
                *(float4*)&smem[nxt + (j * 8 + wrow) * 32 + sc] = g[j];
#pragma unroll
            for (int c = 0; c < 12; ++c) Bc[c] = Bn[c];
        }
    }

    // ---- cross-wave K reduction (red[wv] for wv<4 aliases wave wv's OWN slice,
    //      so phase-1 needs no leading barrier)
    float (*red)[TPB][NEXP] = (float (*)[TPB][NEXP])smem;
    if (wv < 4) {
#pragma unroll
        for (int mt = 0; mt < MT; ++mt)
#pragma unroll
            for (int nt = 0; nt < 4; ++nt)
#pragma unroll
                for (int r = 0; r < 4; ++r) {
                    int tok = 16 * mt + q * 4 + r;
                    int e   = 16 * nt + r16;
                    red[wv][tok][swz_e(tok, e)] = acc[mt][nt][r];
                }
    }
    __syncthreads();
    if (wv >= 4) {
#pragma unroll
        for (int mt = 0; mt < MT; ++mt)
#pragma unroll
            for (int nt = 0; nt < 4; ++nt)
#pragma unroll
                for (int r = 0; r < 4; ++r) {
                    int tok = 16 * mt + q * 4 + r;
                    int e   = 16 * nt + r16;
                    red[wv - 4][tok][swz_e(tok, e)] += acc[mt][nt][r];
                }
    }
    __syncthreads();

    // ---- epilogue: 8 tokens/wave on lanes 0..7 (round-0 proven path)
    if (lane < 8) {
        const int tk = wv * 8 + lane;
        const int t  = tok0 + tk;
        float lg[NEXP];
#pragma unroll
        for (int e = 0; e < NEXP; ++e) {
            int es = swz_e(tk, e);
            lg[e] = ((red[0][tk][es] + red[1][tk][es]) +
                     (red[2][tk][es] + red[3][tk][es])) + Bg[e];
        }
        float* outL = out + (size_t)t * NEXP;
#pragma unroll
        for (int e = 0; e < NEXP; e += 4) {
            float4 v = make_float4(lg[e], lg[e+1], lg[e+2], lg[e+3]);
            *(float4*)(outL + e) = v;
        }
        float mx = lg[0];
#pragma unroll
        for (int e = 1; e < NEXP; ++e) mx = fmaxf(mx, lg[e]);
        float S = 0.f;
#pragma unroll
        for (int e = 0; e < NEXP; ++e) { lg[e] = expf(lg[e] - mx); S += lg[e]; }
#pragma unroll
        for (int e = 0; e < NEXP; ++e) lg[e] = lg[e] / S;

        float v1 = lg[0]; int i1 = 0;
        float v2 = -1.0f; int i2 = 0;
#pragma unroll
        for (int e = 1; e < NEXP; ++e) {
            float rv = lg[e];
            bool g1 = rv > v1;
            bool g2 = rv > v2;
            float nv2 = g1 ? v1 : (g2 ? rv : v2);
            int   ni2 = g1 ? i1 : (g2 ? e  : i2);
            v2 = nv2; i2 = ni2;
            v1 = g1 ? rv : v1;
            i1 = g1 ? e  : i1;
        }
        float den = v1 + v2;
        float w1 = v1 / den, w2 = v2 / den;

        float* outW = out + (size_t)T_TOK * NEXP;
        float* outS = outW + (size_t)T_TOK * 2;
        float* outM = outS + (size_t)T_TOK * 2;
        outW[2*t+0] = w1;        outW[2*t+1] = w2;
        outS[2*t+0] = (float)i1; outS[2*t+1] = (float)i2;

        float* mrow = outM + (size_t)t * 2 * NEXP;
#pragma unroll
        for (int e = 0; e < NEXP; e += 4) {
            float4 a = make_float4(e+0==i1?1.f:0.f, e+1==i1?1.f:0.f,
                                   e+2==i1?1.f:0.f, e+3==i1?1.f:0.f);
            *(float4*)(mrow + e) = a;
            float4 b = make_float4(e+0==i2?1.f:0.f, e+1==i2?1.f:0.f,
                                   e+2==i2?1.f:0.f, e+3==i2?1.f:0.f);
            *(float4*)(mrow + NEXP + e) = b;
        }
    }
}

extern "C" void kernel_launch(void* const* d_in, const int* in_sizes, int n_in,
                              void* d_out, int out_size, void* d_ws, size_t ws_size,
                              hipStream_t stream)
{
    const float* X = (const float*)d_in[0];
    const float* W = (const float*)d_in[1];
    const float* B = (const float*)d_in[2];
    float* out     = (float*)d_out;

    // workspace: packed W fragments, 49152 chunks * 16 B = 768 KiB
    short* Pw = (short*)d_ws;

    hipLaunchKernelGGL(pack_w_kernel, dim3(49152 / 256), dim3(256),
                       0, stream, W, Pw);
    hipLaunchKernelGGL(moe_router_mfma, dim3(T_TOK / TPB), dim3(512),
                       0, stream, X, Pw, B, out);
}